// Round 13
// baseline (199.087 us; speedup 1.0000x reference)
//
#include <hip/hip_runtime.h>
#include <math.h>

#define IMG_W 512
#define IMG_H 512
#define NPLANES 48      // 16 * 3
#define RROWS 64        // output rows per wave (512 = 64*8 exact)
#define NCHUNK 8        // 512 / RROWS
#define NSTRIP 8        // 512 / 64 cols
#define WPB 4           // waves per block (256 threads)
#define NGROUP (NCHUNK / WPB)                  // 2 chunk-groups per strip
#define NBLOCKS (NPLANES * NSTRIP * NGROUP)    // 768 blocks
#define NPAIRS (RROWS / 2 + 5)                 // 37 input row-pairs per wave
#define SSIM_C1 1e-4f
#define SSIM_C2 9e-4f

typedef float f32x2 __attribute__((ext_vector_type(2)));
typedef float f32x4 __attribute__((ext_vector_type(4)));

struct GW { float g[11]; };

__device__ __forceinline__ f32x2 splat2(float v) { return (f32x2){v, v}; }
__device__ __forceinline__ f32x2 fma2(f32x2 a, f32x2 b, f32x2 c) {
  return __builtin_elementwise_fma(a, b, c);
}

// PACKING PROGRAM CLOSED (rounds 8/11): v_pk_*_f32 occupies the FP32 pipe
// for 2x the cycles of the scalar op (157.3 TF spec = scalar rate). Packed
// f32 saves issue slots only; this kernel is not issue-bound (R11: forced
// pk-asm left VALU-busy TIME unchanged, regressed via lost SGPR folding).

// Packed-layout Newton division (verified rounds 6/9/12).
__device__ __forceinline__ f32x2 fdiv_fast2(f32x2 n, f32x2 d) {
  f32x2 r = { __builtin_amdgcn_rcpf(d.x), __builtin_amdgcn_rcpf(d.y) };
  r = r * fma2(-d, r, splat2(2.0f));      // 1 Newton step on reciprocal
  f32x2 q = n * r;
  q = fma2(fma2(-d, q, n), r, q);         // residual correction
  return q;
}

// ORDERING NOTE (root cause of rounds 3/4 failures, fix verified round 5):
// the no-barrier LDS pipeline needs cross-lane write->read ordering; per
// thread the addresses are provably distinct, so the compiler may reorder
// ds ops. HW keeps a wave's DS ops in issue order -> a compiler-only fence
// per iteration (between stage-writes and conv-reads) suffices; with the
// double buffer it also pins the reverse direction at distance 2.
#define LDS_ORDER_FENCE() asm volatile("" ::: "memory")

// ROUND-13 SINGLE CHANGE vs verified R12: __launch_bounds__(256,2)->(256,3).
// Cross-round residency evidence: co-resident waves sit at EXACTLY the
// declared min (2/SIMD = 8/CU) in every configuration (R0-hist ~7, R1 ~7,
// R6/R12 ~8 waves/CU) while VGPR=80 and LDS=15.9KB would permit far more.
// Hypothesis: the declared occupancy floor is what residency is planned
// around. (256,3) caps VGPR at ~168 (kernel uses 80 -> wide margin, no
// spill expected; WRITE_SIZE is the spill tripwire). If null -> the 2-wave
// cap is opaque; ~60us VALU-busy is the floor and R12 is final.
// Other banked lessons: R7 latency-decoupling null; R9 waves_per_eu(2,2)
// pin regressed; R10 VALU->LDS trade regressed ~4:1; R12 final-kernel
// fusion via pre-scaled float atomicAdd (+7us, absmax 0).
__global__ __launch_bounds__(256, 3) void ssim_main(
    const float* __restrict__ A, const float* __restrict__ B,
    const float* __restrict__ F, float* __restrict__ out, GW gw)
{
  __shared__ f32x4 sAB[WPB][2][80];   // (A0,A1,B0,B1) per column
  __shared__ f32x2 sFF[WPB][2][80];   // (F0,F1) per column
  __shared__ double sred[WPB];
  const int b = blockIdx.x;
  const int plane = b / (NSTRIP * NGROUP);
  const int rem   = b % (NSTRIP * NGROUP);
  const int strip = rem / NGROUP;
  const int grp   = rem % NGROUP;
  const int wid = threadIdx.x >> 6;      // wave id 0..3
  const int t   = threadIdx.x & 63;      // lane id
  const int chunk = grp * WPB + wid;     // 0..7
  const int x0 = strip * 64;
  const int y0 = chunk * RROWS;
  const size_t pbase = (size_t)plane * (IMG_W * IMG_H);
  const float* Ap = A + pbase;
  const float* Bp = B + pbase;
  const float* Fp = F + pbase;

  // this wave's private LDS slices
  f32x4 (&mAB)[2][80] = sAB[wid];
  f32x2 (&mFF)[2][80] = sFF[wid];

  const int c  = x0 - 5 + t;                 // primary load column
  const bool cok = (c >= 0) && (c < IMG_W);
  const int c2 = c + 64;                     // halo column (lanes 0..9)
  const bool c2ok = (t < 10) && (c2 < IMG_W);

  // ring[stream][slot]: horizontally-convolved ROW PAIRS, slot = pair mod 6
  f32x2 ring[7][6];
  #pragma unroll
  for (int s = 0; s < 7; ++s)
    #pragma unroll
    for (int k = 0; k < 6; ++k) ring[s][k] = splat2(0.f);

  float acc = 0.f;

  // prefetch registers: 2 rows x 3 arrays x (primary + halo)
  float rA0,rB0,rF0,xA0,xB0,xF0, rA1,rB1,rF1,xA1,xB1,xF1;
  auto load_pair = [&](int ii) {
    const int yin0 = y0 - 5 + 2*ii;
    const int yin1 = yin0 + 1;
    const bool r0 = (yin0 >= 0) && (yin0 < IMG_H);
    const bool r1 = (yin1 >= 0) && (yin1 < IMG_H);
    const size_t o0 = (size_t)yin0 * IMG_W;
    const size_t o1 = (size_t)yin1 * IMG_W;
    rA0 = (r0 && cok) ? Ap[o0 + c] : 0.f;
    rB0 = (r0 && cok) ? Bp[o0 + c] : 0.f;
    rF0 = (r0 && cok) ? Fp[o0 + c] : 0.f;
    rA1 = (r1 && cok) ? Ap[o1 + c] : 0.f;
    rB1 = (r1 && cok) ? Bp[o1 + c] : 0.f;
    rF1 = (r1 && cok) ? Fp[o1 + c] : 0.f;
    xA0 = (r0 && c2ok) ? Ap[o0 + c2] : 0.f;
    xB0 = (r0 && c2ok) ? Bp[o0 + c2] : 0.f;
    xF0 = (r0 && c2ok) ? Fp[o0 + c2] : 0.f;
    xA1 = (r1 && c2ok) ? Ap[o1 + c2] : 0.f;
    xB1 = (r1 && c2ok) ? Bp[o1 + c2] : 0.f;
    xF1 = (r1 && c2ok) ? Fp[o1 + c2] : 0.f;
  };

  load_pair(0);   // preload pair 0

  for (int jj = 0; jj < 7; ++jj) {
    #pragma unroll
    for (int ph = 0; ph < 6; ++ph) {
      const int ii = jj * 6 + ph;            // pair counter; ii % 6 == ph
      if (ii < NPAIRS) {                     // 37 pairs = 74 input rows
        const int buf = ii & 1;
        // --- stage prefetched row pair into LDS (vector, double-buffered) ---
        mAB[buf][t] = (f32x4){rA0, rA1, rB0, rB1};
        mFF[buf][t] = (f32x2){rF0, rF1};
        if (t < 10) {
          mAB[buf][t+64] = (f32x4){xA0, xA1, xB0, xB1};
          mFF[buf][t+64] = (f32x2){xF0, xF1};
        }
        // pin LDS program order: writes above, reads below (see note)
        LDS_ORDER_FENCE();
        // --- issue NEXT pair's global loads; latency hidden under convs ---
        if (ii < NPAIRS - 1) load_pair(ii + 1);
        // --- horizontal 11-tap conv, packed layout over the 2 rows ---
        f32x2 hA=splat2(0.f), hB=splat2(0.f), hF=splat2(0.f),
              hA2=splat2(0.f), hB2=splat2(0.f), hF2=splat2(0.f),
              hAF=splat2(0.f), hBF=splat2(0.f);
        #pragma unroll
        for (int k = 0; k < 11; ++k) {
          const float w = gw.g[k];
          const f32x4 ab = mAB[buf][t+k];     // 1x ds_read_b128
          const f32x2 f  = mFF[buf][t+k];     // 1x ds_read_b64
          const f32x2 a  = {ab.x, ab.y};
          const f32x2 bb = {ab.z, ab.w};
          const f32x2 wv = splat2(w);
          const f32x2 wa = wv*a, wb = wv*bb, wf = wv*f;
          hA += wa; hB += wb; hF += wf;
          hA2 = fma2(wa, a, hA2); hB2 = fma2(wb, bb, hB2); hF2 = fma2(wf, f, hF2);
          hAF = fma2(wa, f, hAF); hBF = fma2(wb, f, hBF);
        }
        // merge variance streams at ring-write (conv linearity): 7 rings
        ring[0][ph]=hA;  ring[1][ph]=hB;  ring[2][ph]=hF;
        ring[3][ph]=hA2+hF2;  ring[4][ph]=hB2+hF2;
        ring[5][ph]=hAF; ring[6][ph]=hBF;

        // --- vertical 11-tap conv + packed SSIM map ---
        if (ii >= 5) {                       // output pair j = ii-5
          f32x2 M[7];
          #pragma unroll
          for (int s = 0; s < 7; ++s) M[s] = splat2(0.f);
          #pragma unroll
          for (int k = 0; k < 11; ++k) {
            const float w = gw.g[k];
            if ((k & 1) == 0) {
              // even tap: lo/hi rows use (.x,.y) of the SAME slot -> packed
              const int p = (ph + 1 + (k >> 1)) % 6;      // compile-time
              const f32x2 wv = splat2(w);
              #pragma unroll
              for (int s = 0; s < 7; ++s) M[s] = fma2(wv, ring[s][p], M[s]);
            } else {
              // odd tap: halves of adjacent slots; scalar on register halves
              const int plo = (ph + 1 + (k >> 1)) % 6;    // compile-time
              const int phi = (plo + 1) % 6;
              #pragma unroll
              for (int s = 0; s < 7; ++s) {
                M[s].x = fmaf(w, ring[s][plo].y, M[s].x);
                M[s].y = fmaf(w, ring[s][phi].x, M[s].y);
              }
            }
          }
          const f32x2 mAv=M[0], mBv=M[1], mFv=M[2];
          const f32x2 vS1=M[3], vS2=M[4], vAF=M[5], vBF=M[6];
          const f32x2 mA2=mAv*mAv, mB2=mBv*mBv, mF2=mFv*mFv,
                      mAF=mAv*mFv, mBF=mBv*mFv;
          const f32x2 sAFv = vAF - mAF, sBFv = vBF - mBF;
          const f32x2 ts1 = vS1 - mA2 - mF2;   // sigmaA^2 + sigmaF^2
          const f32x2 ts2 = vS2 - mB2 - mF2;   // sigmaB^2 + sigmaF^2
          const f32x2 two = splat2(2.f), c1 = splat2(SSIM_C1), c2v = splat2(SSIM_C2);
          const f32x2 n1 = fma2(two, mAF, c1) * fma2(two, sAFv, c2v);
          const f32x2 d1 = (mA2 + mF2 + c1) * (ts1 + c2v);
          const f32x2 n2 = fma2(two, mBF, c1) * fma2(two, sBFv, c2v);
          const f32x2 d2 = (mB2 + mF2 + c1) * (ts2 + c2v);
          const f32x2 q1 = fdiv_fast2(n1, d1);
          const f32x2 q2 = fdiv_fast2(n2, d2);
          // accumulate in row-ascending order (bit-identical to scalar)
          acc += q1.x + q2.x;
          acc += q1.y + q2.y;
        }
      }
    }
  }

  // wave (64-lane) reduction, cross-wave LDS reduce, then ONE pre-scaled
  // float atomicAdd per block straight into out[0] (verified R12: device-
  // coherent across XCDs; harness memsets out before launch; 768 adds of
  // ~3e-4 into ~0.8 -> ~2e-6 error, 100x under threshold).
  float wsum = acc;
  #pragma unroll
  for (int off = 32; off > 0; off >>= 1)
    wsum += __shfl_down(wsum, off, 64);
  if (t == 0) sred[wid] = (double)wsum;
  __syncthreads();
  if (threadIdx.x == 0) {
    const double bsum = sred[0] + sred[1] + sred[2] + sred[3];
    atomicAdd(out, (float)(0.5 * bsum / (double)(16.0 * 3.0 * 512.0 * 512.0)));
  }
}

extern "C" void kernel_launch(void* const* d_in, const int* in_sizes, int n_in,
                              void* d_out, int out_size, void* d_ws, size_t ws_size,
                              hipStream_t stream) {
  const float* A = (const float*)d_in[0];
  const float* B = (const float*)d_in[1];
  const float* F = (const float*)d_in[2];

  GW gw;
  double g[11], s = 0.0;
  for (int i = 0; i < 11; ++i) { g[i] = exp(-((double)((i-5)*(i-5))) / 4.5); s += g[i]; }
  for (int i = 0; i < 11; ++i) gw.g[i] = (float)(g[i] / s);

  hipLaunchKernelGGL(ssim_main, dim3(NBLOCKS), dim3(WPB * 64), 0, stream,
                     A, B, F, (float*)d_out, gw);
}